// Round 1
// baseline (12.623 us; speedup 1.0000x reference)
//
#include <hip/hip_runtime.h>

#define NB 32          // batches
#define LSEQ 4096      // seq len
#define DEMB 768       // emb dim
#define NS 128         // sentences per batch
#define MSL 64         // max sentence len
#define D4 (DEMB / 4)  // 192 float4 per row

// Phase 1: per-batch ragged segment sums + first-max argmax + validity gate.
// One block per batch, one thread per sentence (128 threads = 2 waves).
__global__ void pick_kernel(const int* __restrict__ startends,
                            const float* __restrict__ attention,
                            int2* __restrict__ pick) {
    const int b = blockIdx.x;
    const int s = threadIdx.x;  // 0..127

    const int st = startends[(b * NS + s) * 2 + 0];
    const int en = startends[(b * NS + s) * 2 + 1];
    const float* att = attention + (size_t)b * LSEQ;
    float sum = 0.0f;
    for (int i = st; i < en; ++i) sum += att[i];

    // Lexicographic max over (sum, -idx): strictly-greater wins, tie -> lower idx.
    float bsum = sum;
    int bidx = s;
    #pragma unroll
    for (int off = 32; off > 0; off >>= 1) {
        float osum = __shfl_down(bsum, off, 64);
        int oidx = __shfl_down(bidx, off, 64);
        if (osum > bsum || (osum == bsum && oidx < bidx)) {
            bsum = osum;
            bidx = oidx;
        }
    }

    __shared__ float s_sum[2];
    __shared__ int s_idx[2];
    const int wave = threadIdx.x >> 6;
    if ((threadIdx.x & 63) == 0) {
        s_sum[wave] = bsum;
        s_idx[wave] = bidx;
    }
    __syncthreads();

    if (threadIdx.x == 0) {
        bsum = s_sum[0];
        bidx = s_idx[0];
        if (s_sum[1] > bsum || (s_sum[1] == bsum && s_idx[1] < bidx)) {
            bsum = s_sum[1];
            bidx = s_idx[1];
        }
        int bst = 0, blen = 0;
        if (bsum > 0.0f) {  // reference: valid = max_sum > 0, else (0,0)
            bst = startends[(b * NS + bidx) * 2 + 0];
            blen = startends[(b * NS + bidx) * 2 + 1] - bst;
        }
        pick[b] = make_int2(bst, blen);
    }
}

// Phase 2: out[b, m, :] = (m < blen[b]) ? context[b, bstart[b]+m, :] : 0
// One block per output row (b,m); 192 threads, one float4 each.
__global__ void gather_kernel(const float* __restrict__ context,
                              const int2* __restrict__ pick,
                              float* __restrict__ out) {
    const int bm = blockIdx.x;     // 0..NB*MSL-1
    const int b = bm >> 6;         // / MSL
    const int m = bm & (MSL - 1);  // % MSL
    const int d4 = threadIdx.x;    // 0..191

    const int2 p = pick[b];
    float4 v = make_float4(0.0f, 0.0f, 0.0f, 0.0f);
    if (m < p.y) {
        const float4* src = reinterpret_cast<const float4*>(context);
        v = src[((size_t)b * LSEQ + (size_t)(p.x + m)) * D4 + d4];
    }
    float4* dst = reinterpret_cast<float4*>(out);
    dst[(size_t)bm * D4 + d4] = v;
}

extern "C" void kernel_launch(void* const* d_in, const int* in_sizes, int n_in,
                              void* d_out, int out_size, void* d_ws, size_t ws_size,
                              hipStream_t stream) {
    const int* startends = (const int*)d_in[0];       // [B, S, 2] int32
    const float* attention = (const float*)d_in[1];   // [B, L] f32
    const float* context = (const float*)d_in[2];     // [B, L, D] f32
    float* out = (float*)d_out;                       // [B, M, D] f32
    int2* pick = (int2*)d_ws;                         // [B] (bstart, blen)

    pick_kernel<<<NB, NS, 0, stream>>>(startends, attention, pick);
    gather_kernel<<<NB * MSL, D4, 0, stream>>>(context, pick, out);
}